// Round 13
// baseline (378.838 us; speedup 1.0000x reference)
//
#include <hip/hip_runtime.h>

// MoE: x[8,4096,512]f32, assign[8,4096,2]i32, W1[8,512,2048], b1[8,2048],
//      W2[8,2048,512], b2[8,512] -> out[8,4096,512]f32
// v13 = v12 + G1 restructured to 4m x 4n wave tiles (chunk=512 hid, k32
//       phases) -> X re-reads halved, G1 at 0.5KB/MFMA like G2. Unified 4KB
//       W pieces (2-way-clean swizzle), H in 256-hid halves, uniform vmcnt(4)
//       1-deep ring, slotted bf16 Y output + combine (no atomics).

#define NTOK 32768
#define DIM  512
#define HID  2048
#define NE   8
#define TM   64
#define MAXTILE 128            // 128*64 = 8192 >> n_e (~7680+-85)

#define XBASE 0                // X: 64 rows x 1024B (64 16B-units, swz low3)
#define HBASE 65536            // H half: 64 tok x 256 hid (32 units, swz low3)
#define RBASE 98304            // rings: 8 waves x 2 slots x 4096B
#define LDS_BYTES 163840

typedef __attribute__((ext_vector_type(8))) short short8;
typedef __attribute__((ext_vector_type(4))) float f32x4;
typedef __attribute__((ext_vector_type(4))) unsigned short us4b;
typedef unsigned short ushort_t;

__device__ __forceinline__ unsigned short f2bf(float f) {
  union { float f; unsigned u; } v; v.f = f;
  unsigned r = v.u + 0x7FFFu + ((v.u >> 16) & 1u);  // RNE
  return (unsigned short)(r >> 16);
}
__device__ __forceinline__ float bf2f(unsigned short s) {
  union { unsigned u; float f; } v; v.u = ((unsigned)s) << 16;
  return v.f;
}
__device__ __forceinline__ void g2l16(const void* g, void* l) {
  __builtin_amdgcn_global_load_lds(
      (const __attribute__((address_space(1))) void*)g,
      (__attribute__((address_space(3))) void*)l, 16, 0, 0);
}

#define SCHB __builtin_amdgcn_sched_barrier(0)
#define VMW4 do { asm volatile("s_waitcnt vmcnt(4)" ::: "memory"); SCHB; } while (0)
#define MFMA16(a, b, c) __builtin_amdgcn_mfma_f32_16x16x32_bf16(a, b, c, 0, 0, 0)

// ---------------- prep: W transposes + LDS-ranked routing ----------------
__device__ __forceinline__ void transp_body(const float* __restrict__ src,
                                            ushort_t* __restrict__ dst,
                                            int R, int C, int rb, int cb,
                                            int t, float tile[64][68]) {
  {
    const int tr = t >> 2, tc = (t & 3) * 16;
    const f32x4* s = (const f32x4*)(src + (size_t)(rb + tr) * C + cb + tc);
    f32x4 v0 = __builtin_nontemporal_load(s + 0);
    f32x4 v1 = __builtin_nontemporal_load(s + 1);
    f32x4 v2 = __builtin_nontemporal_load(s + 2);
    f32x4 v3 = __builtin_nontemporal_load(s + 3);
    *(f32x4*)&tile[tr][tc + 0]  = v0;
    *(f32x4*)&tile[tr][tc + 4]  = v1;
    *(f32x4*)&tile[tr][tc + 8]  = v2;
    *(f32x4*)&tile[tr][tc + 12] = v3;
  }
  __syncthreads();
  {
    const int n = t >> 2, ks = (t & 3) * 16;
    short8 o0, o1;
#pragma unroll
    for (int j = 0; j < 8; ++j) o0[j] = (short)f2bf(tile[ks + j][n]);
#pragma unroll
    for (int j = 0; j < 8; ++j) o1[j] = (short)f2bf(tile[ks + 8 + j][n]);
    ushort_t* d = dst + (size_t)(cb + n) * R + rb + ks;
    *(short8*)(d) = o0;
    *(short8*)(d + 8) = o1;
  }
}

__global__ __launch_bounds__(256) void moe_prep(
    const float* __restrict__ W1, const float* __restrict__ W2,
    ushort_t* __restrict__ W1b, ushort_t* __restrict__ W2b,
    const int* __restrict__ assign, int* __restrict__ cnt,
    int* __restrict__ lists) {
  __shared__ float tile[64][68];
  __shared__ int lcnt[NE], gbase[NE];
  const int b = blockIdx.x;
  const int t = threadIdx.x;
  if (b < 2048) {                       // W1: [512][2048] -> [2048][512]
    int e = b >> 8, rem = b & 255;
    int rb = (rem >> 5) * 64, cb = (rem & 31) * 64;
    transp_body(W1 + (size_t)e * DIM * HID, W1b + (size_t)e * HID * DIM,
                DIM, HID, rb, cb, t, tile);
  } else if (b < 4096) {                // W2: [2048][512] -> [512][2048]
    int bb = b - 2048;
    int e = bb >> 8, rem = bb & 255;
    int rb = (rem >> 3) * 64, cb = (rem & 7) * 64;
    transp_body(W2 + (size_t)e * HID * DIM, W2b + (size_t)e * DIM * HID,
                HID, DIM, rb, cb, t, tile);
  } else {                              // routing: LDS histogram + rank
    int tt = (b - 4096) * 256 + t;
    if (t < NE) lcnt[t] = 0;
    __syncthreads();
    int a0 = assign[2 * tt + 0];
    int a1 = assign[2 * tt + 1];
    int r0, r1 = -1;
    r0 = atomicAdd(&lcnt[a0], 1);
    if (a0 != a1) r1 = atomicAdd(&lcnt[a1], 1);
    __syncthreads();
    if (t < NE) gbase[t] = atomicAdd(&cnt[t], lcnt[t]);
    __syncthreads();
    if (a0 == a1) {
      lists[a0 * NTOK + gbase[a0] + r0] = tt | 0x10000;     // dup: both slots
    } else {
      lists[a0 * NTOK + gbase[a0] + r0] = tt;               // slot 0
      lists[a1 * NTOK + gbase[a1] + r1] = tt | (1 << 17);   // slot 1
    }
  }
}

// ---------------- combine: out = 0.5*(Y0 + Y1) ----------------
__global__ __launch_bounds__(256) void moe_combine(
    const ushort_t* __restrict__ Yb, float* __restrict__ out) {
  size_t i = ((size_t)blockIdx.x * 256 + threadIdx.x) * 8;
  short8 y0 = *(const short8*)(Yb + i);
  short8 y1 = *(const short8*)(Yb + (size_t)NTOK * DIM + i);
  f32x4 o0, o1;
#pragma unroll
  for (int j = 0; j < 4; ++j)
    o0[j] = 0.5f * (bf2f((unsigned short)y0[j]) + bf2f((unsigned short)y1[j]));
#pragma unroll
  for (int j = 0; j < 4; ++j)
    o1[j] = 0.5f * (bf2f((unsigned short)y0[4 + j]) + bf2f((unsigned short)y1[4 + j]));
  *(f32x4*)(out + i) = o0;
  *(f32x4*)(out + i + 4) = o1;
}

// ---------- fused expert GEMM: X-resident, 4x4 tiles both GEMMs ----------
__global__ __launch_bounds__(512, 1) void moe_gemm(
    const float* __restrict__ x, const ushort_t* __restrict__ W1b,
    const float* __restrict__ b1, const ushort_t* __restrict__ W2b,
    const float* __restrict__ b2, const int* __restrict__ cnt,
    const int* __restrict__ lists, ushort_t* __restrict__ Yb) {
  extern __shared__ char smem[];

  const int id = blockIdx.x;
  const int e = id & 7;          // expert == XCD (round-robin dispatch)
  const int tile = id >> 3;
  const int n_e = cnt[e];
  const int t0 = tile * TM;
  if (t0 >= n_e) return;

  const int tid = threadIdx.x;
  const int wid = tid >> 6;
  const int lane = tid & 63;
  const int lr = lane & 15, lg = lane >> 4;
  const int lr7 = lr & 7;
  // staging decomposition for unified 4KB W pieces (32 lines x 128B):
  const int lsub = lane >> 3;            // line-within-8
  const int unit = (lane & 7) ^ lsub;    // stored unit at this lane's slot
  const int etahi = unit >> 2;           // row-half selector
  const int kq = unit & 3;               // k 16B-quarter

  char* const ringw = smem + RBASE + wid * 8192;   // 2 slots x 4KB

  // per-lane W bases (pre-swizzled global sources)
  const ushort_t* gW1w = W1b +
      ((size_t)(e * HID + wid * 32 + etahi * 256 + lsub)) * DIM + kq * 8;
  const ushort_t* gW2w = W2b +
      ((size_t)(e * DIM + wid * 64 + etahi * 32 + lsub)) * HID + kq * 8;

  auto stW1 = [&](int c, int p, int sl) {   // 64 hid (2x32 ranges) x 32 k
    const ushort_t* g = gW1w + (size_t)c * (512 * DIM) + p * 32;
    char* d = ringw + sl * 4096 + lane * 16;
    g2l16(g, d);
    g2l16(g + 1 * 8 * DIM, d + 1024);
    g2l16(g + 2 * 8 * DIM, d + 2048);
    g2l16(g + 3 * 8 * DIM, d + 3072);
  };
  auto stW2 = [&](int c, int h, int q, int sl) {  // 64 out x 32 k
    const ushort_t* g = gW2w + c * 512 + h * 256 + q * 32;
    char* d = ringw + sl * 4096 + lane * 16;
    g2l16(g, d);
    g2l16(g + 1 * 8 * HID, d + 1024);
    g2l16(g + 2 * 8 * HID, d + 2048);
    g2l16(g + 3 * 8 * HID, d + 3072);
  };

#define RD_W(dst, mf, SL) \
  dst = *(const short8*)(ringw + (SL) * 4096 + (((mf) & 1) * 16 + lr) * 128 + \
                         (((((mf) >> 1) * 4 + lg) ^ lr7) * 16))

#define G1P(p, SL, ISSUE) do { \
  ISSUE; SCHB; VMW4; \
  short8 wf[4], xf[4]; \
  _Pragma("unroll") for (int mf = 0; mf < 4; ++mf) RD_W(wf[mf], mf, SL); \
  _Pragma("unroll") for (int nf = 0; nf < 4; ++nf) { \
    int u_ = (p) * 4 + lg; int row_ = nf * 16 + lr; \
    xf[nf] = *(const short8*)(smem + XBASE + row_ * 1024 + \
             ((u_ & ~7) | ((u_ & 7) ^ lr7)) * 16); } \
  SCHB; __builtin_amdgcn_s_setprio(1); \
  _Pragma("unroll") for (int mf = 0; mf < 4; ++mf) \
    _Pragma("unroll") for (int nf = 0; nf < 4; ++nf) \
      acc1[mf][nf] = MFMA16(wf[mf], xf[nf], acc1[mf][nf]); \
  __builtin_amdgcn_s_setprio(0); SCHB; \
} while (0)

#define G2P(q, SL, ISSUE) do { \
  ISSUE; SCHB; VMW4; \
  short8 wf[4], hf[4]; \
  _Pragma("unroll") for (int mf = 0; mf < 4; ++mf) RD_W(wf[mf], mf, SL); \
  _Pragma("unroll") for (int nf = 0; nf < 4; ++nf) { \
    int u_ = (q) * 4 + lg; int row_ = nf * 16 + lr; \
    hf[nf] = *(const short8*)(smem + HBASE + row_ * 512 + \
             ((u_ & ~7) | ((u_ & 7) ^ lr7)) * 16); } \
  SCHB; __builtin_amdgcn_s_setprio(1); \
  _Pragma("unroll") for (int mf = 0; mf < 4; ++mf) \
    _Pragma("unroll") for (int nf = 0; nf < 4; ++nf) \
      acc2[mf][nf] = MFMA16(wf[mf], hf[nf], acc2[mf][nf]); \
  __builtin_amdgcn_s_setprio(0); SCHB; \
} while (0)

// H handoff: bias+relu for half h (acc1 rows 2h,2h+1), packed b64 writes
#define HANDOFF(h) do { \
  asm volatile("s_waitcnt lgkmcnt(0)" ::: "memory"); \
  __builtin_amdgcn_s_barrier(); SCHB; \
  { const float* b1p = b1 + (size_t)e * HID + c * 512 + (h) * 256 + \
                       wid * 32 + lg * 4; \
    f32x4 bq0 = *(const f32x4*)(b1p); \
    f32x4 bq1 = *(const f32x4*)(b1p + 16); \
    _Pragma("unroll") for (int m2 = 0; m2 < 2; ++m2) { \
      int hl = wid * 32 + m2 * 16 + lg * 4; int u = hl >> 3; \
      _Pragma("unroll") for (int nf = 0; nf < 4; ++nf) { \
        int tokr = nf * 16 + lr; \
        us4b pk; \
        pk.x = f2bf(fmaxf(acc1[(h)*2+m2][nf][0] + (m2 ? bq1[0] : bq0[0]), 0.f)); \
        pk.y = f2bf(fmaxf(acc1[(h)*2+m2][nf][1] + (m2 ? bq1[1] : bq0[1]), 0.f)); \
        pk.z = f2bf(fmaxf(acc1[(h)*2+m2][nf][2] + (m2 ? bq1[2] : bq0[2]), 0.f)); \
        pk.w = f2bf(fmaxf(acc1[(h)*2+m2][nf][3] + (m2 ? bq1[3] : bq0[3]), 0.f)); \
        *(us4b*)(smem + HBASE + tokr * 512 + \
                 ((u & ~7) | ((u & 7) ^ (tokr & 7))) * 16 + (lg & 1) * 8) = pk; \
      } } } \
  SCHB; \
  asm volatile("s_waitcnt lgkmcnt(0)" ::: "memory"); \
  __builtin_amdgcn_s_barrier(); SCHB; \
} while (0)

  // ---- prologue: X-stage (fp32->bf16, NT, swizzled), drain, prime ----
  {
    int row = tid >> 3;
    int idx = t0 + row;
    int tok = lists[e * NTOK + (idx < n_e ? idx : 0)] & 0xFFFF;
    const float* xr = x + (size_t)tok * DIM;
#pragma unroll
    for (int i = 0; i < 8; ++i) {
      int u = (tid & 7) + 8 * i;
      f32x4 v0 = __builtin_nontemporal_load((const f32x4*)(xr + u * 8));
      f32x4 v1 = __builtin_nontemporal_load((const f32x4*)(xr + u * 8 + 4));
      short8 pk;
      pk[0] = (short)f2bf(v0.x); pk[1] = (short)f2bf(v0.y);
      pk[2] = (short)f2bf(v0.z); pk[3] = (short)f2bf(v0.w);
      pk[4] = (short)f2bf(v1.x); pk[5] = (short)f2bf(v1.y);
      pk[6] = (short)f2bf(v1.z); pk[7] = (short)f2bf(v1.w);
      int su = (u & ~7) | ((u & 7) ^ (row & 7));
      *(short8*)(smem + XBASE + row * 1024 + su * 16) = pk;
    }
  }
  __syncthreads();        // full drain; X visible block-wide

  stW1(0, 0, 0);          // prime phase-0 piece into slot 0

  f32x4 acc2[4][4];
#pragma unroll
  for (int i = 0; i < 4; ++i)
#pragma unroll
    for (int j = 0; j < 4; ++j) acc2[i][j] = f32x4{0.f, 0.f, 0.f, 0.f};

#pragma unroll 1
  for (int c = 0; c < 4; ++c) {
    f32x4 acc1[4][4];
#pragma unroll
    for (int i = 0; i < 4; ++i)
#pragma unroll
      for (int j = 0; j < 4; ++j) acc1[i][j] = f32x4{0.f, 0.f, 0.f, 0.f};

    // ===== G1: 16 phases of k32 over DIM=512 =====
    G1P(0,  0, stW1(c, 1, 1));
    G1P(1,  1, stW1(c, 2, 0));
    G1P(2,  0, stW1(c, 3, 1));
    G1P(3,  1, stW1(c, 4, 0));
    G1P(4,  0, stW1(c, 5, 1));
    G1P(5,  1, stW1(c, 6, 0));
    G1P(6,  0, stW1(c, 7, 1));
    G1P(7,  1, stW1(c, 8, 0));
    G1P(8,  0, stW1(c, 9, 1));
    G1P(9,  1, stW1(c, 10, 0));
    G1P(10, 0, stW1(c, 11, 1));
    G1P(11, 1, stW1(c, 12, 0));
    G1P(12, 0, stW1(c, 13, 1));
    G1P(13, 1, stW1(c, 14, 0));
    G1P(14, 0, stW1(c, 15, 1));
    G1P(15, 1, stW2(c, 0, 0, 0));

    HANDOFF(0);

    // ===== G2 half 0: k = hid [c*512, +256) =====
    G2P(0, 0, stW2(c, 0, 1, 1));
    G2P(1, 1, stW2(c, 0, 2, 0));
    G2P(2, 0, stW2(c, 0, 3, 1));
    G2P(3, 1, stW2(c, 0, 4, 0));
    G2P(4, 0, stW2(c, 0, 5, 1));
    G2P(5, 1, stW2(c, 0, 6, 0));
    G2P(6, 0, stW2(c, 0, 7, 1));
    G2P(7, 1, stW2(c, 1, 0, 0));

    HANDOFF(1);

    // ===== G2 half 1: k = hid [c*512+256, +256) =====
    G2P(0, 0, stW2(c, 1, 1, 1));
    G2P(1, 1, stW2(c, 1, 2, 0));
    G2P(2, 0, stW2(c, 1, 3, 1));
    G2P(3, 1, stW2(c, 1, 4, 0));
    G2P(4, 0, stW2(c, 1, 5, 1));
    G2P(5, 1, stW2(c, 1, 6, 0));
    G2P(6, 0, stW2(c, 1, 7, 1));
    G2P(7, 1, { int cn = (c < 3) ? c + 1 : 0; stW1(cn, 0, 0); });
  }
  asm volatile("s_waitcnt vmcnt(0)" ::: "memory");   // drain wrap prefetch
  SCHB;

  // ---- epilogue: slotted non-atomic stores: Y[slot][tok] = y + b2 ----
  f32x4 b2q[4];
#pragma unroll
  for (int mf = 0; mf < 4; ++mf)
    b2q[mf] = *(const f32x4*)(b2 + e * DIM + wid * 64 + mf * 16 + lg * 4);

#pragma unroll
  for (int nf = 0; nf < 4; ++nf) {
    int gi = t0 + nf * 16 + lr;
    if (gi >= n_e) continue;
    int ent = lists[e * NTOK + gi];
    int tok = ent & 0xFFFF;
    int slot = (ent >> 17) & 1;
    size_t base = ((size_t)(slot * NTOK + tok)) * DIM + wid * 64 + lg * 4;
#pragma unroll
    for (int mf = 0; mf < 4; ++mf) {
      f32x4 y = acc2[mf][nf] + b2q[mf];
      us4b pk;
      pk.x = f2bf(y[0]); pk.y = f2bf(y[1]); pk.z = f2bf(y[2]); pk.w = f2bf(y[3]);
      *(us4b*)(Yb + base + mf * 16) = pk;
      if (ent & 0x10000)   // dup token: same value to slot 1
        *(us4b*)(Yb + base + (size_t)NTOK * DIM + mf * 16) = pk;
    }
  }
}

extern "C" void kernel_launch(void* const* d_in, const int* in_sizes, int n_in,
                              void* d_out, int out_size, void* d_ws, size_t ws_size,
                              hipStream_t stream) {
  const float* x      = (const float*)d_in[0];
  const int*   assign = (const int*)d_in[1];
  const float* W1     = (const float*)d_in[2];
  const float* b1     = (const float*)d_in[3];
  const float* W2     = (const float*)d_in[4];
  const float* b2     = (const float*)d_in[5];
  float* out = (float*)d_out;

  char* ws = (char*)d_ws;
  int* cnt   = (int*)ws;
  int* lists = (int*)(ws + 1024);
  ushort_t* W1b = (ushort_t*)(ws + (2ull << 20));               // 16 MB (+pad)
  ushort_t* W2b = (ushort_t*)(ws + (2ull << 20) + 18874368ull); // 16 MB
  ushort_t* Yb  = (ushort_t*)(ws + (2ull << 20) + 2ull * 18874368ull); // 64 MB

  (void)hipMemsetAsync(cnt, 0, 256, stream);

  moe_prep<<<4096 + NTOK / 256, 256, 0, stream>>>(W1, W2, W1b, W2b,
                                                  assign, cnt, lists);

  (void)hipFuncSetAttribute((const void*)moe_gemm,
                            hipFuncAttributeMaxDynamicSharedMemorySize, LDS_BYTES);
  moe_gemm<<<NE * MAXTILE, 512, LDS_BYTES, stream>>>(x, W1b, b1, W2b, b2,
                                                     cnt, lists, Yb);

  moe_combine<<<NTOK * DIM / 2048, 256, 0, stream>>>(Yb, out);
}

// Round 14
// 371.420 us; speedup vs baseline: 1.0200x; 1.0200x over previous
//
#include <hip/hip_runtime.h>

// MoE: x[8,4096,512]f32, assign[8,4096,2]i32, W1[8,512,2048], b1[8,2048],
//      W2[8,2048,512], b2[8,512] -> out[8,4096,512]f32
// v14 = v12 engine (2-phase-ahead issue, uniform vmcnt(4), opaque asm b1,
//       slotted Y + combine) + v13's 4x4 G1 tile (chunk=512, k32 phases) +
//       unified 2KB W pieces with conflict-free us^(r&3) swizzle.

#define NTOK 32768
#define DIM  512
#define HID  2048
#define NE   8
#define TM   64
#define MAXTILE 128            // 128*64 = 8192 >> n_e (~7680+-85)

#define XBASE 0                // X: 64 rows x 1024B (64 16B-units, swz low3)
#define HBASE 65536            // H half: 64 tok x 256 hid (32 units, swz low3)
#define RBASE 98304            // rings: 8 waves x 4 slots x 2048B
#define LDS_BYTES 163840

typedef __attribute__((ext_vector_type(8))) short short8;
typedef __attribute__((ext_vector_type(4))) float f32x4;
typedef __attribute__((ext_vector_type(4))) unsigned short us4b;
typedef unsigned short ushort_t;

__device__ __forceinline__ unsigned short f2bf(float f) {
  union { float f; unsigned u; } v; v.f = f;
  unsigned r = v.u + 0x7FFFu + ((v.u >> 16) & 1u);  // RNE
  return (unsigned short)(r >> 16);
}
__device__ __forceinline__ float bf2f(unsigned short s) {
  union { unsigned u; float f; } v; v.u = ((unsigned)s) << 16;
  return v.f;
}
__device__ __forceinline__ void g2l16(const void* g, void* l) {
  __builtin_amdgcn_global_load_lds(
      (const __attribute__((address_space(1))) void*)g,
      (__attribute__((address_space(3))) void*)l, 16, 0, 0);
}

#define SCHB __builtin_amdgcn_sched_barrier(0)
#define VMW4 do { asm volatile("s_waitcnt vmcnt(4)" ::: "memory"); SCHB; } while (0)
#define MFMA16(a, b, c) __builtin_amdgcn_mfma_f32_16x16x32_bf16(a, b, c, 0, 0, 0)

// ---------------- prep: W transposes + LDS-ranked routing ----------------
__device__ __forceinline__ void transp_body(const float* __restrict__ src,
                                            ushort_t* __restrict__ dst,
                                            int R, int C, int rb, int cb,
                                            int t, float tile[64][68]) {
  {
    const int tr = t >> 2, tc = (t & 3) * 16;
    const f32x4* s = (const f32x4*)(src + (size_t)(rb + tr) * C + cb + tc);
    f32x4 v0 = __builtin_nontemporal_load(s + 0);
    f32x4 v1 = __builtin_nontemporal_load(s + 1);
    f32x4 v2 = __builtin_nontemporal_load(s + 2);
    f32x4 v3 = __builtin_nontemporal_load(s + 3);
    *(f32x4*)&tile[tr][tc + 0]  = v0;
    *(f32x4*)&tile[tr][tc + 4]  = v1;
    *(f32x4*)&tile[tr][tc + 8]  = v2;
    *(f32x4*)&tile[tr][tc + 12] = v3;
  }
  __syncthreads();
  {
    const int n = t >> 2, ks = (t & 3) * 16;
    short8 o0, o1;
#pragma unroll
    for (int j = 0; j < 8; ++j) o0[j] = (short)f2bf(tile[ks + j][n]);
#pragma unroll
    for (int j = 0; j < 8; ++j) o1[j] = (short)f2bf(tile[ks + 8 + j][n]);
    ushort_t* d = dst + (size_t)(cb + n) * R + rb + ks;
    *(short8*)(d) = o0;
    *(short8*)(d + 8) = o1;
  }
}

__global__ __launch_bounds__(256) void moe_prep(
    const float* __restrict__ W1, const float* __restrict__ W2,
    ushort_t* __restrict__ W1b, ushort_t* __restrict__ W2b,
    const int* __restrict__ assign, int* __restrict__ cnt,
    int* __restrict__ lists) {
  __shared__ float tile[64][68];
  __shared__ int lcnt[NE], gbase[NE];
  const int b = blockIdx.x;
  const int t = threadIdx.x;
  if (b < 2048) {                       // W1: [512][2048] -> [2048][512]
    int e = b >> 8, rem = b & 255;
    int rb = (rem >> 5) * 64, cb = (rem & 31) * 64;
    transp_body(W1 + (size_t)e * DIM * HID, W1b + (size_t)e * HID * DIM,
                DIM, HID, rb, cb, t, tile);
  } else if (b < 4096) {                // W2: [2048][512] -> [512][2048]
    int bb = b - 2048;
    int e = bb >> 8, rem = bb & 255;
    int rb = (rem >> 3) * 64, cb = (rem & 7) * 64;
    transp_body(W2 + (size_t)e * HID * DIM, W2b + (size_t)e * DIM * HID,
                HID, DIM, rb, cb, t, tile);
  } else {                              // routing: LDS histogram + rank
    int tt = (b - 4096) * 256 + t;
    if (t < NE) lcnt[t] = 0;
    __syncthreads();
    int a0 = assign[2 * tt + 0];
    int a1 = assign[2 * tt + 1];
    int r0, r1 = -1;
    r0 = atomicAdd(&lcnt[a0], 1);
    if (a0 != a1) r1 = atomicAdd(&lcnt[a1], 1);
    __syncthreads();
    if (t < NE) gbase[t] = atomicAdd(&cnt[t], lcnt[t]);
    __syncthreads();
    if (a0 == a1) {
      lists[a0 * NTOK + gbase[a0] + r0] = tt | 0x10000;     // dup: both slots
    } else {
      lists[a0 * NTOK + gbase[a0] + r0] = tt;               // slot 0
      lists[a1 * NTOK + gbase[a1] + r1] = tt | (1 << 17);   // slot 1
    }
  }
}

// ---------------- combine: out = 0.5*(Y0 + Y1) ----------------
__global__ __launch_bounds__(256) void moe_combine(
    const ushort_t* __restrict__ Yb, float* __restrict__ out) {
  size_t i = ((size_t)blockIdx.x * 256 + threadIdx.x) * 8;
  short8 y0 = *(const short8*)(Yb + i);
  short8 y1 = *(const short8*)(Yb + (size_t)NTOK * DIM + i);
  f32x4 o0, o1;
#pragma unroll
  for (int j = 0; j < 4; ++j)
    o0[j] = 0.5f * (bf2f((unsigned short)y0[j]) + bf2f((unsigned short)y1[j]));
#pragma unroll
  for (int j = 0; j < 4; ++j)
    o1[j] = 0.5f * (bf2f((unsigned short)y0[4 + j]) + bf2f((unsigned short)y1[4 + j]));
  *(f32x4*)(out + i) = o0;
  *(f32x4*)(out + i + 4) = o1;
}

// ---------- fused expert GEMM: X-resident, 4x4 tiles, 2-phase-ahead ----------
__global__ __launch_bounds__(512, 1) void moe_gemm(
    const float* __restrict__ x, const ushort_t* __restrict__ W1b,
    const float* __restrict__ b1, const ushort_t* __restrict__ W2b,
    const float* __restrict__ b2, const int* __restrict__ cnt,
    const int* __restrict__ lists, ushort_t* __restrict__ Yb) {
  extern __shared__ char smem[];

  const int id = blockIdx.x;
  const int e = id & 7;          // expert == XCD (round-robin dispatch)
  const int tile = id >> 3;
  const int n_e = cnt[e];
  const int t0 = tile * TM;
  if (t0 >= n_e) return;

  const int tid = threadIdx.x;
  const int wid = tid >> 6;
  const int lane = tid & 63;
  const int lr = lane & 15, lg = lane >> 4;
  const int lr7 = lr & 7;
  const int lr3 = lr & 3;

  char* const ringw = smem + RBASE + wid * 8192;   // 4 slots x 2KB

  // per-lane W bases (pre-swizzled: lane covers row (lane>>2), k-q (lane&3)^((lane>>2)&3))
  const ushort_t* gW1L = W1b +
      ((size_t)(e * HID + wid * 32 + (lane >> 2))) * DIM +
      ((lane & 3) ^ ((lane >> 2) & 3)) * 8;
  const ushort_t* gW2L = W2b +
      ((size_t)(e * DIM + wid * 64 + (lane >> 2))) * HID +
      ((lane & 3) ^ ((lane >> 2) & 3)) * 8;
  const float* b1e = b1 + (size_t)e * HID + wid * 32 + lg * 4;

  // stage G1 pieces for phase p of chunk c into slots sA (mf0,1) / sB (mf2,3)
  auto stW1 = [&](int c, int p, int sA, int sB) {
    const ushort_t* g = gW1L + (size_t)(c * 512) * DIM + p * 32;
    char* dA = ringw + sA * 2048 + lane * 16;
    char* dB = ringw + sB * 2048 + lane * 16;
    g2l16(g, dA);
    g2l16(g + (size_t)16 * DIM, dA + 1024);
    g2l16(g + (size_t)256 * DIM, dB);
    g2l16(g + (size_t)272 * DIM, dB + 1024);
  };
  // stage G2 pieces for half h phase q of chunk c
  auto stW2 = [&](int c, int h, int q, int sA, int sB) {
    const ushort_t* g = gW2L + c * 512 + h * 256 + q * 32;
    char* dA = ringw + sA * 2048 + lane * 16;
    char* dB = ringw + sB * 2048 + lane * 16;
    g2l16(g, dA);
    g2l16(g + (size_t)16 * HID, dA + 1024);
    g2l16(g + (size_t)32 * HID, dB);
    g2l16(g + (size_t)48 * HID, dB + 1024);
  };

#define B1LOAD(d0, d1, d2, d3, BI) do { \
  const float* a_ = b1e + (size_t)(BI) * 512; \
  asm volatile("global_load_dwordx4 %0, %4, off\n\t" \
               "global_load_dwordx4 %1, %4, off offset:64\n\t" \
               "global_load_dwordx4 %2, %4, off offset:1024\n\t" \
               "global_load_dwordx4 %3, %4, off offset:1088" \
               : "=&v"(d0), "=&v"(d1), "=&v"(d2), "=&v"(d3) : "v"(a_)); \
} while (0)

// W frag read: piece slot S, 16-row half m2; row = m2*16+lr, unit lg^(r&3)
#define RD_W(dst, S, m2) \
  dst = *(const short8*)(ringw + (S) * 2048 + ((m2) * 16 + lr) * 64 + \
                         ((lg ^ lr3) * 16))
#define XRD(dst, nf, p) do { \
  const int u_ = (p) * 4 + lg; const int row_ = (nf) * 16 + lr; \
  dst = *(const short8*)(smem + XBASE + row_ * 1024 + \
        ((u_ & ~7) | ((u_ & 7) ^ lr7)) * 16); } while (0)
#define HRD(dst, nf, q) do { \
  const int u_ = (q) * 4 + lg; const int row_ = (nf) * 16 + lr; \
  dst = *(const short8*)(smem + HBASE + row_ * 512 + \
        ((u_ & ~7) | ((u_ & 7) ^ lr7)) * 16); } while (0)

#define G1P(p, S0, S1, ISSUE) do { \
  VMW4; \
  short8 wf0, wf1, wf2, wf3; \
  RD_W(wf0, S0, 0); RD_W(wf1, S0, 1); RD_W(wf2, S1, 0); RD_W(wf3, S1, 1); \
  SCHB; \
  short8 xf0, xf1, xf2, xf3; \
  XRD(xf0, 0, p); XRD(xf1, 1, p); XRD(xf2, 2, p); XRD(xf3, 3, p); \
  SCHB; \
  asm volatile("s_waitcnt lgkmcnt(4)" ::: "memory"); SCHB; \
  ISSUE; SCHB; \
  __builtin_amdgcn_s_setprio(1); \
  acc1[0][0] = MFMA16(wf0, xf0, acc1[0][0]); acc1[0][1] = MFMA16(wf0, xf1, acc1[0][1]); \
  acc1[0][2] = MFMA16(wf0, xf2, acc1[0][2]); acc1[0][3] = MFMA16(wf0, xf3, acc1[0][3]); \
  acc1[1][0] = MFMA16(wf1, xf0, acc1[1][0]); acc1[1][1] = MFMA16(wf1, xf1, acc1[1][1]); \
  acc1[1][2] = MFMA16(wf1, xf2, acc1[1][2]); acc1[1][3] = MFMA16(wf1, xf3, acc1[1][3]); \
  acc1[2][0] = MFMA16(wf2, xf0, acc1[2][0]); acc1[2][1] = MFMA16(wf2, xf1, acc1[2][1]); \
  acc1[2][2] = MFMA16(wf2, xf2, acc1[2][2]); acc1[2][3] = MFMA16(wf2, xf3, acc1[2][3]); \
  acc1[3][0] = MFMA16(wf3, xf0, acc1[3][0]); acc1[3][1] = MFMA16(wf3, xf1, acc1[3][1]); \
  acc1[3][2] = MFMA16(wf3, xf2, acc1[3][2]); acc1[3][3] = MFMA16(wf3, xf3, acc1[3][3]); \
  __builtin_amdgcn_s_setprio(0); SCHB; \
} while (0)

#define G2P(q, S0, S1, ISSUE) do { \
  VMW4; \
  short8 wf0, wf1, wf2, wf3; \
  RD_W(wf0, S0, 0); RD_W(wf1, S0, 1); RD_W(wf2, S1, 0); RD_W(wf3, S1, 1); \
  SCHB; \
  short8 hf0, hf1, hf2, hf3; \
  HRD(hf0, 0, q); HRD(hf1, 1, q); HRD(hf2, 2, q); HRD(hf3, 3, q); \
  SCHB; \
  asm volatile("s_waitcnt lgkmcnt(4)" ::: "memory"); SCHB; \
  ISSUE; SCHB; \
  __builtin_amdgcn_s_setprio(1); \
  acc2[0][0] = MFMA16(wf0, hf0, acc2[0][0]); acc2[0][1] = MFMA16(wf0, hf1, acc2[0][1]); \
  acc2[0][2] = MFMA16(wf0, hf2, acc2[0][2]); acc2[0][3] = MFMA16(wf0, hf3, acc2[0][3]); \
  acc2[1][0] = MFMA16(wf1, hf0, acc2[1][0]); acc2[1][1] = MFMA16(wf1, hf1, acc2[1][1]); \
  acc2[1][2] = MFMA16(wf1, hf2, acc2[1][2]); acc2[1][3] = MFMA16(wf1, hf3, acc2[1][3]); \
  acc2[2][0] = MFMA16(wf2, hf0, acc2[2][0]); acc2[2][1] = MFMA16(wf2, hf1, acc2[2][1]); \
  acc2[2][2] = MFMA16(wf2, hf2, acc2[2][2]); acc2[2][3] = MFMA16(wf2, hf3, acc2[2][3]); \
  acc2[3][0] = MFMA16(wf3, hf0, acc2[3][0]); acc2[3][1] = MFMA16(wf3, hf1, acc2[3][1]); \
  acc2[3][2] = MFMA16(wf3, hf2, acc2[3][2]); acc2[3][3] = MFMA16(wf3, hf3, acc2[3][3]); \
  __builtin_amdgcn_s_setprio(0); SCHB; \
} while (0)

// H handoff: bias+relu for half h (acc1 mf = 2h, 2h+1), packed b64 writes
#define HANDOFF(h, Q0, Q1) do { \
  asm volatile("s_waitcnt lgkmcnt(0)" ::: "memory"); \
  __builtin_amdgcn_s_barrier(); SCHB; \
  _Pragma("unroll") for (int m2 = 0; m2 < 2; ++m2) { \
    f32x4 bq_ = m2 ? (Q1) : (Q0); \
    int hl_ = wid * 32 + m2 * 16 + lg * 4; int u_ = hl_ >> 3; \
    _Pragma("unroll") for (int nf = 0; nf < 4; ++nf) { \
      int tokr_ = nf * 16 + lr; \
      us4b pk_; \
      pk_.x = f2bf(fmaxf(acc1[(h) * 2 + m2][nf][0] + bq_[0], 0.f)); \
      pk_.y = f2bf(fmaxf(acc1[(h) * 2 + m2][nf][1] + bq_[1], 0.f)); \
      pk_.z = f2bf(fmaxf(acc1[(h) * 2 + m2][nf][2] + bq_[2], 0.f)); \
      pk_.w = f2bf(fmaxf(acc1[(h) * 2 + m2][nf][3] + bq_[3], 0.f)); \
      *(us4b*)(smem + HBASE + tokr_ * 512 + \
               ((u_ & ~7) | ((u_ & 7) ^ (tokr_ & 7))) * 16 + (lg & 1) * 8) = pk_; \
    } } \
  SCHB; \
  asm volatile("s_waitcnt lgkmcnt(0)" ::: "memory"); \
  __builtin_amdgcn_s_barrier(); SCHB; \
} while (0)

// acc1 mf mapping: 0 = A-low16, 1 = A-high16 (hid +0..31); 2,3 = +256..287
#define CHUNK(C, BU0, BU1, BU2, BU3, BN0, BN1, BN2, BN3) do { \
  f32x4 acc1[4][4]; \
  _Pragma("unroll") for (int i_ = 0; i_ < 4; ++i_) \
    _Pragma("unroll") for (int j_ = 0; j_ < 4; ++j_) \
      acc1[i_][j_] = f32x4{0.f, 0.f, 0.f, 0.f}; \
  G1P(0,  0, 1, { B1LOAD(BN0, BN1, BN2, BN3, ((C) + 1) & 3); \
                  stW1((C), 2, 0, 1); }); \
  G1P(1,  2, 3, stW1((C), 3, 2, 3)); \
  G1P(2,  0, 1, stW1((C), 4, 0, 1)); \
  G1P(3,  2, 3, stW1((C), 5, 2, 3)); \
  G1P(4,  0, 1, stW1((C), 6, 0, 1)); \
  G1P(5,  2, 3, stW1((C), 7, 2, 3)); \
  G1P(6,  0, 1, stW1((C), 8, 0, 1)); \
  G1P(7,  2, 3, stW1((C), 9, 2, 3)); \
  G1P(8,  0, 1, stW1((C), 10, 0, 1)); \
  G1P(9,  2, 3, stW1((C), 11, 2, 3)); \
  G1P(10, 0, 1, stW1((C), 12, 0, 1)); \
  G1P(11, 2, 3, stW1((C), 13, 2, 3)); \
  G1P(12, 0, 1, stW1((C), 14, 0, 1)); \
  G1P(13, 2, 3, stW1((C), 15, 2, 3)); \
  G1P(14, 0, 1, stW2((C), 0, 0, 0, 1)); \
  G1P(15, 2, 3, stW2((C), 0, 1, 2, 3)); \
  HANDOFF(0, BU0, BU1); \
  G2P(0, 0, 1, stW2((C), 0, 2, 0, 1)); \
  G2P(1, 2, 3, stW2((C), 0, 3, 2, 3)); \
  G2P(2, 0, 1, stW2((C), 0, 4, 0, 1)); \
  G2P(3, 2, 3, stW2((C), 0, 5, 2, 3)); \
  G2P(4, 0, 1, stW2((C), 0, 6, 0, 1)); \
  G2P(5, 2, 3, stW2((C), 0, 7, 2, 3)); \
  G2P(6, 0, 1, stW2((C), 1, 0, 0, 1)); \
  G2P(7, 2, 3, stW2((C), 1, 1, 2, 3)); \
  HANDOFF(1, BU2, BU3); \
  G2P(0, 0, 1, stW2((C), 1, 2, 0, 1)); \
  G2P(1, 2, 3, stW2((C), 1, 3, 2, 3)); \
  G2P(2, 0, 1, stW2((C), 1, 4, 0, 1)); \
  G2P(3, 2, 3, stW2((C), 1, 5, 2, 3)); \
  G2P(4, 0, 1, stW2((C), 1, 6, 0, 1)); \
  G2P(5, 2, 3, stW2((C), 1, 7, 2, 3)); \
  G2P(6, 0, 1, stW1(((C) + 1) & 3, 0, 0, 1)); \
  G2P(7, 2, 3, stW1(((C) + 1) & 3, 1, 2, 3)); \
} while (0)

  // ---- prologue: X-stage (fp32->bf16, NT, swizzled), drain, prime ----
  {
    int row = tid >> 3;
    int idx = t0 + row;
    int tok = lists[e * NTOK + (idx < n_e ? idx : 0)] & 0xFFFF;
    const float* xr = x + (size_t)tok * DIM;
#pragma unroll
    for (int i = 0; i < 8; ++i) {
      int u = (tid & 7) + 8 * i;
      f32x4 v0 = __builtin_nontemporal_load((const f32x4*)(xr + u * 8));
      f32x4 v1 = __builtin_nontemporal_load((const f32x4*)(xr + u * 8 + 4));
      short8 pk;
      pk[0] = (short)f2bf(v0.x); pk[1] = (short)f2bf(v0.y);
      pk[2] = (short)f2bf(v0.z); pk[3] = (short)f2bf(v0.w);
      pk[4] = (short)f2bf(v1.x); pk[5] = (short)f2bf(v1.y);
      pk[6] = (short)f2bf(v1.z); pk[7] = (short)f2bf(v1.w);
      int su = (u & ~7) | ((u & 7) ^ (row & 7));
      *(short8*)(smem + XBASE + row * 1024 + su * 16) = pk;
    }
  }
  __syncthreads();   // full drain: no compiler VMEM in the pipeline past here

  f32x4 bA0, bA1, bA2, bA3, bB0, bB1, bB2, bB3;
  B1LOAD(bA0, bA1, bA2, bA3, 0);
  stW1(0, 0, 0, 1);
  stW1(0, 1, 2, 3);
  SCHB;

  f32x4 acc2[4][4];
#pragma unroll
  for (int i = 0; i < 4; ++i)
#pragma unroll
    for (int j = 0; j < 4; ++j) acc2[i][j] = f32x4{0.f, 0.f, 0.f, 0.f};

#pragma unroll 1
  for (int cc = 0; cc < 2; ++cc) {
    const int c0 = cc * 2;
    CHUNK(c0,     bA0, bA1, bA2, bA3, bB0, bB1, bB2, bB3);
    CHUNK(c0 + 1, bB0, bB1, bB2, bB3, bA0, bA1, bA2, bA3);
  }
  asm volatile("s_waitcnt vmcnt(0)" ::: "memory");   // drain wrap prefetch
  SCHB;
  asm volatile("" :: "v"(bA0), "v"(bA1), "v"(bA2), "v"(bA3));  // keep tail alive

  // ---- epilogue: slotted non-atomic stores: Y[slot][tok] = y + b2 ----
  f32x4 b2q[4];
#pragma unroll
  for (int mf = 0; mf < 4; ++mf)
    b2q[mf] = *(const f32x4*)(b2 + e * DIM + wid * 64 + mf * 16 + lg * 4);

#pragma unroll
  for (int nf = 0; nf < 4; ++nf) {
    int gi = t0 + nf * 16 + lr;
    if (gi >= n_e) continue;
    int ent = lists[e * NTOK + gi];
    int tok = ent & 0xFFFF;
    int slot = (ent >> 17) & 1;
    size_t base = ((size_t)(slot * NTOK + tok)) * DIM + wid * 64 + lg * 4;
#pragma unroll
    for (int mf = 0; mf < 4; ++mf) {
      f32x4 y = acc2[mf][nf] + b2q[mf];
      us4b pk;
      pk.x = f2bf(y[0]); pk.y = f2bf(y[1]); pk.z = f2bf(y[2]); pk.w = f2bf(y[3]);
      *(us4b*)(Yb + base + mf * 16) = pk;
      if (ent & 0x10000)   // dup token: same value to slot 1
        *(us4b*)(Yb + base + (size_t)NTOK * DIM + mf * 16) = pk;
    }
  }
}

extern "C" void kernel_launch(void* const* d_in, const int* in_sizes, int n_in,
                              void* d_out, int out_size, void* d_ws, size_t ws_size,
                              hipStream_t stream) {
  const float* x      = (const float*)d_in[0];
  const int*   assign = (const int*)d_in[1];
  const float* W1     = (const float*)d_in[2];
  const float* b1     = (const float*)d_in[3];
  const float* W2     = (const float*)d_in[4];
  const float* b2     = (const float*)d_in[5];
  float* out = (float*)d_out;

  char* ws = (char*)d_ws;
  int* cnt   = (int*)ws;
  int* lists = (int*)(ws + 1024);
  ushort_t* W1b = (ushort_t*)(ws + (2ull << 20));               // 16 MB (+pad)
  ushort_t* W2b = (ushort_t*)(ws + (2ull << 20) + 18874368ull); // 16 MB
  ushort_t* Yb  = (ushort_t*)(ws + (2ull << 20) + 2ull * 18874368ull); // 64 MB

  (void)hipMemsetAsync(cnt, 0, 256, stream);

  moe_prep<<<4096 + NTOK / 256, 256, 0, stream>>>(W1, W2, W1b, W2b,
                                                  assign, cnt, lists);

  (void)hipFuncSetAttribute((const void*)moe_gemm,
                            hipFuncAttributeMaxDynamicSharedMemorySize, LDS_BYTES);
  moe_gemm<<<NE * MAXTILE, 512, LDS_BYTES, stream>>>(x, W1b, b1, W2b, b2,
                                                     cnt, lists, Yb);

  moe_combine<<<NTOK * DIM / 2048, 256, 0, stream>>>(Yb, out);
}